// Round 2
// baseline (838.803 us; speedup 1.0000x reference)
//
#include <hip/hip_runtime.h>
#include <hip/hip_bf16.h>

// Problem constants (fixed by setup_inputs)
#define TT    2209          // (2*24-1)^2 relative-position table entries
#define NB    32            // batch
#define NH    16            // heads
#define ND    512           // RPB hidden dim
#define WH    24            // window height/width
#define NW    576           // 24*24 window tokens
#define NP    577           // NW + num_prefix_tokens(=1)
#define PLANE (NP * NP)     // 332929 floats per (b,h) output plane

// ---------------------------------------------------------------------------
// Stage 1: bias_t[b][h][t] = (relu((coords_table[t] + pos[b]) @ W1 + b1) @ W2)[h]
// Weights are read with wave-uniform (readfirstlane-forced SGPR) addresses so
// the compiler emits s_load_* — scalar cache traffic, zero VALU/LDS cost.
// Head-major output so stage 2's per-plane gathers live in one 8.8 KB window.
// ---------------------------------------------------------------------------
__global__ __launch_bounds__(256) void cpb_mlp(
    const float* __restrict__ glob_pos,     // (1, 32, 4)
    const float* __restrict__ coords_table, // (2209, 2)
    const float* __restrict__ W1,           // (2, 512)
    const float* __restrict__ b1,           // (512,)
    const float* __restrict__ W2,           // (512, 16)
    float* __restrict__ bias_t)             // (32, 16, 2209) scratch
{
    const unsigned gid = blockIdx.x * 256u + threadIdx.x;
    const bool live = gid < (unsigned)(NB * TT);
    const unsigned b = live ? gid / TT : 0u;
    const unsigned t = live ? gid - b * TT : 0u;

    // pos transform (per-batch; 2 divides + 2 log2 per thread — trivial)
    const float g0 = glob_pos[b * 4 + 0];
    const float g1 = glob_pos[b * 4 + 1];
    const float g2 = glob_pos[b * 4 + 2];
    const float g3 = glob_pos[b * 4 + 3];
    float px = g2 / g0 * 8.0f;
    float py = g3 / g1 * 8.0f;
    // sign(x)*log2(|x|+1)/log2(8), then *2-1
    px = copysignf(log2f(fabsf(px) + 1.0f) * (1.0f / 3.0f), px) * 2.0f - 1.0f;
    py = copysignf(log2f(fabsf(py) + 1.0f) * (1.0f / 3.0f), py) * 2.0f - 1.0f;

    const float tx = coords_table[t * 2 + 0] + px;
    const float ty = coords_table[t * 2 + 1] + py;

    float acc[NH];
#pragma unroll
    for (int h = 0; h < NH; ++h) acc[h] = 0.0f;

#pragma unroll 2
    for (int d0 = 0; d0 < ND; d0 += 4) {
        // Force SGPR addressing: readfirstlane makes the index provably
        // uniform -> compiler emits s_load_dwordx4 / merged dwordx16.
        const int du = __builtin_amdgcn_readfirstlane(d0);
        const float4 wa = *reinterpret_cast<const float4*>(W1 + du);        // row 0
        const float4 wb = *reinterpret_cast<const float4*>(W1 + ND + du);   // row 1
        const float4 bb = *reinterpret_cast<const float4*>(b1 + du);

        float hv[4];
        hv[0] = fmaxf(fmaf(tx, wa.x, fmaf(ty, wb.x, bb.x)), 0.0f);
        hv[1] = fmaxf(fmaf(tx, wa.y, fmaf(ty, wb.y, bb.y)), 0.0f);
        hv[2] = fmaxf(fmaf(tx, wa.z, fmaf(ty, wb.z, bb.z)), 0.0f);
        hv[3] = fmaxf(fmaf(tx, wa.w, fmaf(ty, wb.w, bb.w)), 0.0f);

#pragma unroll
        for (int k = 0; k < 4; ++k) {
            const float* w2row = W2 + (size_t)(du + k) * NH;   // 16 floats, uniform
#pragma unroll
            for (int h = 0; h < NH; ++h) {
                acc[h] = fmaf(hv[k], w2row[h], acc[h]);        // v_fmac, 1 SGPR src
            }
        }
    }

    if (live) {
        // head-major write; lanes have consecutive t -> coalesced per h
#pragma unroll
        for (int h = 0; h < NH; ++h) {
            bias_t[(b * NH + h) * TT + t] = acc[h];
        }
    }
}

// ---------------------------------------------------------------------------
// Stage 2: out[b][h][i][j] = (i&&j) ? bias_t[b][h][idx(i-1,j-1)] : 0
// where idx(q,k) = (qh-kh+23)*47 + (qw-kw+23)  (analytic rpi — no load, no
// dependent-load chain; all divisors compile-time -> magic-mul).
// Flat float4 stores (16 B/lane, aligned); per-element carry over the odd
// row length 577 keeps vector alignment intact across row/plane boundaries.
// ---------------------------------------------------------------------------
__global__ __launch_bounds__(256) void cpb_scatter(
    const float* __restrict__ bias_t, // (32, 16, 2209)
    float* __restrict__ out)          // (32, 16, 577, 577)
{
    constexpr unsigned TOTAL = (unsigned)NB * NH * PLANE; // 170,459,648 (div by 4)
    const unsigned gid  = blockIdx.x * 256u + threadIdx.x;
    const unsigned base = gid * 4u;
    if (base >= TOTAL) return;

    unsigned p   = base / PLANE;          // plane = b*16 + h
    unsigned rem = base - p * PLANE;
    unsigned i   = rem / NP;
    unsigned j   = rem - i * NP;

    const float* __restrict__ plane = bias_t + (size_t)p * TT;

    float vals[4];
#pragma unroll
    for (int k = 0; k < 4; ++k) {
        float v = 0.0f;
        if (i != 0u && j != 0u) {
            const unsigned q  = i - 1u;
            const unsigned kk = j - 1u;
            const unsigned qh = q / WH,  qw = q - qh * WH;
            const unsigned kh = kk / WH, kw = kk - kh * WH;
            const unsigned idx = (qh - kh + (WH - 1u)) * (2u * WH - 1u)
                               + (qw - kw + (WH - 1u));
            v = plane[idx];
        }
        vals[k] = v;
        if (++j == (unsigned)NP) {        // carry into next row / plane
            j = 0u;
            if (++i == (unsigned)NP) { i = 0u; ++p; plane += TT; }
        }
    }

    float4 o;
    o.x = vals[0]; o.y = vals[1]; o.z = vals[2]; o.w = vals[3];
    *reinterpret_cast<float4*>(out + base) = o;
}

// ---------------------------------------------------------------------------
extern "C" void kernel_launch(void* const* d_in, const int* in_sizes, int n_in,
                              void* d_out, int out_size, void* d_ws, size_t ws_size,
                              hipStream_t stream)
{
    const float* glob_pos     = (const float*)d_in[0];
    const float* coords_table = (const float*)d_in[1];
    // d_in[2] = rpi — unused (computed analytically in stage 2)
    const float* W1           = (const float*)d_in[3];
    const float* b1           = (const float*)d_in[4];
    const float* W2           = (const float*)d_in[5];
    // d_in[6] = num_prefix_tokens (always 1; NP/PLANE are compile-time)

    float* out    = (float*)d_out;
    float* bias_t = (float*)d_ws;   // 32*16*2209 floats = 4.5 MB scratch

    // Stage 1: 32*2209 = 70,688 threads
    const int n1 = NB * TT;
    const int blocks1 = (n1 + 255) / 256;
    cpb_mlp<<<blocks1, 256, 0, stream>>>(glob_pos, coords_table, W1, b1, W2, bias_t);

    // Stage 2: one float4 per thread over the whole output
    const unsigned total   = (unsigned)NB * NH * PLANE;
    const unsigned groups  = total / 4u;
    const unsigned blocks2 = (groups + 255u) / 256u;
    cpb_scatter<<<blocks2, 256, 0, stream>>>(bias_t, out);
}